// Round 2
// baseline (473.080 us; speedup 1.0000x reference)
//
#include <hip/hip_runtime.h>

// ---------------------------------------------------------------------------
// MultiHeadAttention: B=4, S=2048, D=1024, H=16, Dh=64.
// I/O is FP32 (per reference); bf16 MFMA internally, fp32 accumulate.
// Pipeline: 3x proj GEMM (f32 in -> bf16 out) -> V transpose ->
//           flash attention (bf16) -> out GEMM (bf16 in -> f32 out).
// ---------------------------------------------------------------------------

typedef __bf16 bf16x8 __attribute__((ext_vector_type(8)));
typedef float  f32x4  __attribute__((ext_vector_type(4)));

#define LOG2E 1.44269504088896340736f

__device__ inline unsigned short f2bf(float f) {  // RNE f32 -> bf16 bits
  unsigned int u = __float_as_uint(f);
  u = u + 0x7FFF + ((u >> 16) & 1);
  return (unsigned short)(u >> 16);
}
__device__ inline void gload16(const void* g, void* l) {  // 16B global->LDS DMA
  __builtin_amdgcn_global_load_lds(
      (const __attribute__((address_space(1))) void*)g,
      (__attribute__((address_space(3))) void*)l, 16, 0, 0);
}
__device__ inline bf16x8 cvt8(const float* p) {  // 8 f32 -> bf16x8 (RNE cvt)
  float4 a = *(const float4*)p, b = *(const float4*)(p + 4);
  bf16x8 v;
  v[0] = (__bf16)a.x; v[1] = (__bf16)a.y; v[2] = (__bf16)a.z; v[3] = (__bf16)a.w;
  v[4] = (__bf16)b.x; v[5] = (__bf16)b.y; v[6] = (__bf16)b.z; v[7] = (__bf16)b.w;
  return v;
}

// ---------------------------------------------------------------------------
// Projection GEMM: C_bf16(M,N) = A_f32(M,K) @ W_f32(N,K)^T + bias_f32.
// 128x128 tile, BK=32, 256 thr (4 waves 2x2 of 64x64), mfma 16x16x32 bf16.
// Staging converts f32->bf16 in registers, 16B ds_write. grid (N/128, M/128).
// ---------------------------------------------------------------------------
__global__ __launch_bounds__(256, 2) void gemm_proj(
    const float* __restrict__ A, const float* __restrict__ W,
    const float* __restrict__ bias, unsigned short* __restrict__ C,
    int M, int N, int K) {
  __shared__ __align__(16) unsigned short Al[128 * 32];
  __shared__ __align__(16) unsigned short Bl[128 * 32];
  const int tid = threadIdx.x;
  const int lane = tid & 63, w = tid >> 6;
  const int lid = lane & 15, lg = lane >> 4;
  const int n0 = blockIdx.x * 128, m0 = blockIdx.y * 128;
  const int wm = (w & 1) * 64, wn = (w >> 1) * 64;

  f32x4 acc[4][4];
#pragma unroll
  for (int i = 0; i < 4; i++)
#pragma unroll
    for (int j = 0; j < 4; j++) acc[i][j] = (f32x4){0.f, 0.f, 0.f, 0.f};

  for (int kt = 0; kt < K; kt += 32) {
    __syncthreads();
#pragma unroll
    for (int i = 0; i < 2; i++) {
      int c = i * 256 + tid;  // chunk: row r = c>>2, k-offset (c&3)*8
      int r = c >> 2, ko = (c & 3) * 8;
      *(bf16x8*)(&Al[c * 8]) = cvt8(A + (size_t)(m0 + r) * K + kt + ko);
      *(bf16x8*)(&Bl[c * 8]) = cvt8(W + (size_t)(n0 + r) * K + kt + ko);
    }
    __syncthreads();
    bf16x8 af[4], bfr[4];
#pragma unroll
    for (int mi = 0; mi < 4; mi++)
      af[mi] = *(const bf16x8*)(&Al[(wm + mi * 16 + lid) * 32 + lg * 8]);
#pragma unroll
    for (int ni = 0; ni < 4; ni++)
      bfr[ni] = *(const bf16x8*)(&Bl[(wn + ni * 16 + lid) * 32 + lg * 8]);
#pragma unroll
    for (int mi = 0; mi < 4; mi++)
#pragma unroll
      for (int ni = 0; ni < 4; ni++)
        acc[mi][ni] = __builtin_amdgcn_mfma_f32_16x16x32_bf16(af[mi], bfr[ni],
                                                              acc[mi][ni], 0, 0, 0);
  }
#pragma unroll
  for (int ni = 0; ni < 4; ni++) {
    int col = n0 + wn + ni * 16 + lid;
    float bv = bias[col];
#pragma unroll
    for (int mi = 0; mi < 4; mi++)
#pragma unroll
      for (int r = 0; r < 4; r++) {
        int row = m0 + wm + mi * 16 + lg * 4 + r;
        C[(size_t)row * N + col] = f2bf(acc[mi][ni][r] + bv);
      }
  }
}

// ---------------------------------------------------------------------------
// Output GEMM: C_f32(M,N) = A_bf16(M,K) @ W_f32(N,K)^T + bias_f32.
// A staged via global_load_lds (16B DMA); W staged with f32->bf16 convert.
// ---------------------------------------------------------------------------
__global__ __launch_bounds__(256, 2) void gemm_out(
    const unsigned short* __restrict__ A, const float* __restrict__ W,
    const float* __restrict__ bias, float* __restrict__ C,
    int M, int N, int K) {
  __shared__ __align__(16) unsigned short Al[128 * 32];
  __shared__ __align__(16) unsigned short Bl[128 * 32];
  const int tid = threadIdx.x;
  const int lane = tid & 63, w = tid >> 6;
  const int lid = lane & 15, lg = lane >> 4;
  const int n0 = blockIdx.x * 128, m0 = blockIdx.y * 128;
  const int wm = (w & 1) * 64, wn = (w >> 1) * 64;

  f32x4 acc[4][4];
#pragma unroll
  for (int i = 0; i < 4; i++)
#pragma unroll
    for (int j = 0; j < 4; j++) acc[i][j] = (f32x4){0.f, 0.f, 0.f, 0.f};

  for (int kt = 0; kt < K; kt += 32) {
    __syncthreads();
#pragma unroll
    for (int i = 0; i < 2; i++) {
      int c = i * 256 + tid;
      int r = c >> 2, ko = (c & 3) * 8;
      gload16(A + (size_t)(m0 + r) * K + kt + ko, &Al[c * 8]);
      *(bf16x8*)(&Bl[c * 8]) = cvt8(W + (size_t)(n0 + r) * K + kt + ko);
    }
    __syncthreads();
    bf16x8 af[4], bfr[4];
#pragma unroll
    for (int mi = 0; mi < 4; mi++)
      af[mi] = *(const bf16x8*)(&Al[(wm + mi * 16 + lid) * 32 + lg * 8]);
#pragma unroll
    for (int ni = 0; ni < 4; ni++)
      bfr[ni] = *(const bf16x8*)(&Bl[(wn + ni * 16 + lid) * 32 + lg * 8]);
#pragma unroll
    for (int mi = 0; mi < 4; mi++)
#pragma unroll
      for (int ni = 0; ni < 4; ni++)
        acc[mi][ni] = __builtin_amdgcn_mfma_f32_16x16x32_bf16(af[mi], bfr[ni],
                                                              acc[mi][ni], 0, 0, 0);
  }
#pragma unroll
  for (int ni = 0; ni < 4; ni++) {
    int col = n0 + wn + ni * 16 + lid;
    float bv = bias[col];
#pragma unroll
    for (int mi = 0; mi < 4; mi++)
#pragma unroll
      for (int r = 0; r < 4; r++) {
        int row = m0 + wm + mi * 16 + lg * 4 + r;
        C[(size_t)row * N + col] = acc[mi][ni][r] + bv;
      }
  }
}

// ---------------------------------------------------------------------------
// V transpose: bf16 (B,S,H,Dh) -> (B*H, Dh, S). 64x64 tiles via LDS.
// grid: (S/64, B*H), 256 thr
// ---------------------------------------------------------------------------
__global__ void tr_v(const unsigned short* __restrict__ Vp,
                     unsigned short* __restrict__ Vt) {
  __shared__ __align__(16) unsigned short T[64 * 72];
  const int tid = threadIdx.x;
  const int s0 = blockIdx.x * 64, bh = blockIdx.y;
  const int b = bh >> 4, h = bh & 15;
#pragma unroll
  for (int i = 0; i < 2; i++) {
    int c = i * 256 + tid;
    int r = c >> 3, off = (c & 7) * 8;
    *(uint4*)(&T[r * 72 + off]) =
        *(const uint4*)(Vp + (size_t)(b * 2048 + s0 + r) * 1024 + h * 64 + off);
  }
  __syncthreads();
#pragma unroll
  for (int i = 0; i < 2; i++) {
    int c = i * 256 + tid;
    int d = c >> 3, off = (c & 7) * 8;
    ushort4 lo, hi;
    lo.x = T[(off + 0) * 72 + d]; lo.y = T[(off + 1) * 72 + d];
    lo.z = T[(off + 2) * 72 + d]; lo.w = T[(off + 3) * 72 + d];
    hi.x = T[(off + 4) * 72 + d]; hi.y = T[(off + 5) * 72 + d];
    hi.z = T[(off + 6) * 72 + d]; hi.w = T[(off + 7) * 72 + d];
    unsigned short* dst = Vt + (size_t)(bh * 64 + d) * 2048 + s0 + off;
    *(ushort4*)(dst) = lo;
    *(ushort4*)(dst + 4) = hi;
  }
}

// ---------------------------------------------------------------------------
// Flash attention (all-bf16 operands, fp32 softmax/accum).
// 1 block = (bh, 128 q rows); 16 key-iters of 128.
// S^T = K.Q^T so P-regs pack along the key dim; Q frags in registers.
// grid: (S/128, B*H), 256 thr (4 waves, 32 q-rows each)
// ---------------------------------------------------------------------------
__global__ __launch_bounds__(256, 2) void attn(
    const unsigned short* __restrict__ Qp,   // (B*S, 1024)
    const unsigned short* __restrict__ Kp,   // (B*S, 1024)
    const unsigned short* __restrict__ Vt,   // (B*H, 64, 2048)
    const int* __restrict__ maskp,           // (B, 2048)
    unsigned short* __restrict__ ctx) {      // (B*S, 1024)
  __shared__ __align__(16) unsigned short Klds[128 * 72];   // [key][64+8pad]
  __shared__ __align__(16) unsigned short Vlds[64 * 136];   // [d][128+8pad]
  __shared__ __align__(16) unsigned short Plds[128 * 136];  // [q][128+8pad]
  __shared__ __align__(16) float mbias[128];

  const int tid = threadIdx.x;
  const int lane = tid & 63, w = tid >> 6;
  const int lid = lane & 15, lg = lane >> 4;
  const int q0 = blockIdx.x * 128, bh = blockIdx.y;
  const int b = bh >> 4, h = bh & 15;
  const int wq = w * 32;

  bf16x8 qf[2][2];
#pragma unroll
  for (int nt = 0; nt < 2; nt++)
#pragma unroll
    for (int ks = 0; ks < 2; ks++) {
      int qrow = b * 2048 + q0 + wq + nt * 16 + lid;
      qf[nt][ks] = *(const bf16x8*)(Qp + (size_t)qrow * 1024 + h * 64 + ks * 32 + lg * 8);
    }

  f32x4 O[2][4];
#pragma unroll
  for (int qt = 0; qt < 2; qt++)
#pragma unroll
    for (int dt = 0; dt < 4; dt++) O[qt][dt] = (f32x4){0.f, 0.f, 0.f, 0.f};
  float mrow[2] = {-1e30f, -1e30f};
  float lrow[2] = {0.f, 0.f};

  const unsigned short* Kg = Kp + (size_t)(b * 2048) * 1024 + h * 64;
  const unsigned short* Vg = Vt + (size_t)bh * 64 * 2048;
  const int* mg = maskp + b * 2048;

  for (int kt = 0; kt < 16; kt++) {
    const int k0 = kt * 128;
    __syncthreads();  // prev iter's K/V/P reads done
#pragma unroll
    for (int i = 0; i < 4; i++) {
      int c = i * 256 + tid;
      int r = c >> 3, off = (c & 7) * 8;
      *(uint4*)(&Klds[r * 72 + off]) =
          *(const uint4*)(Kg + (size_t)(k0 + r) * 1024 + off);
    }
#pragma unroll
    for (int i = 0; i < 4; i++) {
      int c = i * 256 + tid;
      int d = c >> 4, off = (c & 15) * 8;
      *(uint4*)(&Vlds[d * 136 + off]) =
          *(const uint4*)(Vg + (size_t)d * 2048 + k0 + off);
    }
    if (tid < 128) mbias[tid] = (mg[k0 + tid] == 0) ? -1e9f : 0.0f;
    __syncthreads();

    // S^T = K.Q^T : accS[mt][nt], lane holds (key=mt*16+lg*4+r, q=nt*16+lid)
    f32x4 accS[8][2];
#pragma unroll
    for (int mt = 0; mt < 8; mt++) {
      accS[mt][0] = (f32x4){0.f, 0.f, 0.f, 0.f};
      accS[mt][1] = (f32x4){0.f, 0.f, 0.f, 0.f};
    }
#pragma unroll
    for (int ks = 0; ks < 2; ks++)
#pragma unroll
      for (int mt = 0; mt < 8; mt++) {
        bf16x8 a = *(const bf16x8*)(&Klds[(mt * 16 + lid) * 72 + ks * 32 + lg * 8]);
        accS[mt][0] = __builtin_amdgcn_mfma_f32_16x16x32_bf16(a, qf[0][ks], accS[mt][0], 0, 0, 0);
        accS[mt][1] = __builtin_amdgcn_mfma_f32_16x16x32_bf16(a, qf[1][ks], accS[mt][1], 0, 0, 0);
      }

    float alpha[2];
#pragma unroll
    for (int nt = 0; nt < 2; nt++) {
      float mx = -1e30f;
#pragma unroll
      for (int mt = 0; mt < 8; mt++) {
        const f32x4 mb4 = *(const f32x4*)(&mbias[mt * 16 + lg * 4]);
#pragma unroll
        for (int r = 0; r < 4; r++) {
          float s = accS[mt][nt][r] * 0.125f + mb4[r];
          accS[mt][nt][r] = s;
          mx = fmaxf(mx, s);
        }
      }
      mx = fmaxf(mx, __shfl_xor(mx, 16));
      mx = fmaxf(mx, __shfl_xor(mx, 32));
      float mnew = fmaxf(mrow[nt], mx);
      alpha[nt] = __builtin_amdgcn_exp2f((mrow[nt] - mnew) * LOG2E);
      mrow[nt] = mnew;
      float lsum = 0.f;
#pragma unroll
      for (int mt = 0; mt < 8; mt++) {
        float p0 = __builtin_amdgcn_exp2f((accS[mt][nt][0] - mnew) * LOG2E);
        float p1 = __builtin_amdgcn_exp2f((accS[mt][nt][1] - mnew) * LOG2E);
        float p2 = __builtin_amdgcn_exp2f((accS[mt][nt][2] - mnew) * LOG2E);
        float p3 = __builtin_amdgcn_exp2f((accS[mt][nt][3] - mnew) * LOG2E);
        lsum += p0 + p1 + p2 + p3;
        ushort4 pk;
        pk.x = f2bf(p0); pk.y = f2bf(p1); pk.z = f2bf(p2); pk.w = f2bf(p3);
        *(ushort4*)(&Plds[(wq + nt * 16 + lid) * 136 + mt * 16 + lg * 4]) = pk;
      }
      lsum += __shfl_xor(lsum, 16);
      lsum += __shfl_xor(lsum, 32);
      lrow[nt] = lrow[nt] * alpha[nt] + lsum;
    }

#pragma unroll
    for (int qt = 0; qt < 2; qt++)
#pragma unroll
      for (int r = 0; r < 4; r++) {
        float a_r = __shfl(alpha[qt], (lane & 48) | (lg * 4 + r));
#pragma unroll
        for (int dt = 0; dt < 4; dt++) O[qt][dt][r] *= a_r;
      }

    __syncthreads();  // P visible

#pragma unroll
    for (int k4 = 0; k4 < 4; k4++) {
      bf16x8 bv[4];
#pragma unroll
      for (int dt = 0; dt < 4; dt++)
        bv[dt] = *(const bf16x8*)(&Vlds[(dt * 16 + lid) * 136 + k4 * 32 + lg * 8]);
#pragma unroll
      for (int qt = 0; qt < 2; qt++) {
        bf16x8 a = *(const bf16x8*)(&Plds[(wq + qt * 16 + lid) * 136 + k4 * 32 + lg * 8]);
#pragma unroll
        for (int dt = 0; dt < 4; dt++)
          O[qt][dt] = __builtin_amdgcn_mfma_f32_16x16x32_bf16(a, bv[dt], O[qt][dt], 0, 0, 0);
      }
    }
  }

#pragma unroll
  for (int qt = 0; qt < 2; qt++)
#pragma unroll
    for (int r = 0; r < 4; r++) {
      float lv = __shfl(lrow[qt], (lane & 48) | (lg * 4 + r));
      float inv = 1.0f / lv;
      int qrow = b * 2048 + q0 + wq + qt * 16 + lg * 4 + r;
#pragma unroll
      for (int dt = 0; dt < 4; dt++)
        ctx[(size_t)qrow * 1024 + h * 64 + dt * 16 + lid] = f2bf(O[qt][dt][r] * inv);
    }
}

// ---------------------------------------------------------------------------
extern "C" void kernel_launch(void* const* d_in, const int* in_sizes, int n_in,
                              void* d_out, int out_size, void* d_ws, size_t ws_size,
                              hipStream_t stream) {
  const float* q  = (const float*)d_in[0];
  const float* k  = (const float*)d_in[1];
  const float* v  = (const float*)d_in[2];
  const int*   mk = (const int*)d_in[3];
  const float* Wq = (const float*)d_in[4];
  const float* bq = (const float*)d_in[5];
  const float* Wk = (const float*)d_in[6];
  const float* bk = (const float*)d_in[7];
  const float* Wv = (const float*)d_in[8];
  const float* bv = (const float*)d_in[9];
  const float* Wo = (const float*)d_in[10];
  const float* bo = (const float*)d_in[11];

  const size_t NTOK = (size_t)8192 * 1024;
  unsigned short* Qp  = (unsigned short*)d_ws;        // bf16 intermediates
  unsigned short* Kp  = Qp + NTOK;
  unsigned short* Vp  = Kp + NTOK;
  unsigned short* Vt  = Vp + NTOK;
  unsigned short* ctx = Vp;  // Vp dead after tr_v; reuse as attention output

  dim3 gg(8, 64), gb(256);
  gemm_proj<<<gg, gb, 0, stream>>>(q, Wq, bq, Qp, 8192, 1024, 1024);
  gemm_proj<<<gg, gb, 0, stream>>>(k, Wk, bk, Kp, 8192, 1024, 1024);
  gemm_proj<<<gg, gb, 0, stream>>>(v, Wv, bv, Vp, 8192, 1024, 1024);
  tr_v<<<dim3(32, 64), 256, 0, stream>>>(Vp, Vt);
  attn<<<dim3(16, 64), 256, 0, stream>>>(Qp, Kp, Vt, mk, ctx);
  gemm_out<<<gg, gb, 0, stream>>>(ctx, Wo, bo, (float*)d_out, 8192, 1024, 1024);
}